// Round 13
// baseline (312.479 us; speedup 1.0000x reference)
//
#include <hip/hip_runtime.h>
#include <math.h>
#include <stdint.h>

#define N_ROWS 2048
#define DIM    512
#define VOCAB  32000
#define S_LEN  400
#define BATCH  32
#define NT     (VOCAB / 128)      // 250 N-tiles
#define LOG_CLIP -46.0517018598809136f   // log(1e-20)
#define LOG2E  1.4426950408889634f
#define HSZ    1024               // fixup LDS hash slots (>= 2*S_LEN, pow2)

typedef __attribute__((ext_vector_type(8))) short short8;
typedef __attribute__((ext_vector_type(8))) unsigned short ushort8v;
typedef __attribute__((ext_vector_type(4))) float floatx4;

__device__ inline unsigned short f32_to_bf16(float f) {
    union { float f; unsigned u; } v; v.f = f;
    unsigned u = v.u;
    return (unsigned short)((u + 0x7FFFu + ((u >> 16) & 1u)) >> 16);   // RNE
}
__device__ inline float bf16_to_f32(unsigned short h) {
    union { unsigned u; float f; } v; v.u = ((unsigned)h) << 16;
    return v.f;
}

// ---------------- kernel 0: fused f32 -> bf16 cast for W and hidden ----------------
__global__ void cast2_bf16_kernel(const float* __restrict__ srcW,
                                  unsigned short* __restrict__ dstW, unsigned n4w,
                                  const float* __restrict__ srcH,
                                  unsigned short* __restrict__ dstH, unsigned n4h) {
    const unsigned total = n4w + n4h;
    for (unsigned i = blockIdx.x * blockDim.x + threadIdx.x; i < total;
         i += gridDim.x * blockDim.x) {
        const float4* s = (i < n4w) ? reinterpret_cast<const float4*>(srcW) + i
                                    : reinterpret_cast<const float4*>(srcH) + (i - n4w);
        ushort4* d = (i < n4w) ? reinterpret_cast<ushort4*>(dstW) + i
                               : reinterpret_cast<ushort4*>(dstH) + (i - n4w);
        float4 v = *s;
        ushort4 o;
        o.x = f32_to_bf16(v.x); o.y = f32_to_bf16(v.y);
        o.z = f32_to_bf16(v.z); o.w = f32_to_bf16(v.w);
        *d = o;
    }
}

// ---------------- kernel 2: bf16 MFMA GEMM, counted-vmcnt TRIPLE-buffer ---------
// TBK=32, 3 LDS buffers. Per K-step:
//   compute(cur) -> lgkmcnt(0)+schedbar+s_barrier   (all waves done READING cur)
//   stage(cur, t+3)                                 (4 gload_lds/wave into cur)
//   vmcnt(8)+schedbar+s_barrier                     (t+1 READY; t+2,t+3 in flight)
// Two compute phases (~500+ device cyc) cover even HBM-miss latency (~900 cyc)
// for the ~10% of staging that misses L2 (FETCH 53MB of ~520MB staged).
#define TBM 128
#define TBN 128
#define TBK 32
#define KTILES (DIM / TBK)        // 16

__global__ __launch_bounds__(256) void gemm_mfma_kernel(
        const unsigned short* __restrict__ A,
        const unsigned short* __restrict__ B,
        const float* __restrict__ bias,
        unsigned short* __restrict__ C,          // bf16 logits
        float2* __restrict__ partials) {
    // 3 bufs x (A 4096 | B 4096) ushorts = 48 KB; epilogue reuses [64][136] (8696)
    __shared__ unsigned short shm[24576];
    __shared__ float pmax[TBM];
    __shared__ float psum[TBM];

    const int tid  = threadIdx.x;
    const int lane = tid & 63;
    const int w    = tid >> 6;          // wave 0..3
    const int wr   = w >> 1, wc = w & 1;

    // chunked XCD swizzle (nwg=4000, 4000%8==0 -> bijective), then by-fastest:
    // 16 consecutive swz ids on one XCD share the same B panel.
    const unsigned nwg  = (unsigned)(VOCAB / TBN) * (N_ROWS / TBM);   // 4000
    const unsigned orig = blockIdx.x;
    const unsigned swz  = (orig & 7u) * (nwg / 8u) + (orig >> 3);
    const int bm = (int)(swz & 15u) * TBM;      // N_ROWS/TBM = 16
    const int bn = (int)(swz >> 4)  * TBN;      // 0..249

    const int l15 = lane & 15;
    const int kg  = lane >> 4;          // 0..3

    floatx4 acc[4][4] = {};

    // stage one 128x32 A-tile + B-tile into buf: 4 gload_lds (wave-collective 1KB each)
    auto stage = [&](int buf, int k0) {
        unsigned short* As = shm + buf * 8192;
        unsigned short* Bs = As + 4096;
        #pragma unroll
        for (int r = 0; r < 2; ++r) {
            const int chunk = r * 256 + w * 64 + lane;
            const int row = chunk >> 2, cg = chunk & 3;      // 4 chunks (64B) per row
            __builtin_amdgcn_global_load_lds(
                (const __attribute__((address_space(1))) void*)(A + (size_t)(bm + row) * DIM + k0 + cg * 8),
                (__attribute__((address_space(3))) void*)(As + (size_t)(r * 256 + w * 64) * 8),
                16, 0, 0);
        }
        #pragma unroll
        for (int r = 0; r < 2; ++r) {
            const int chunk = r * 256 + w * 64 + lane;
            const int row = chunk >> 2, cg = chunk & 3;
            __builtin_amdgcn_global_load_lds(
                (const __attribute__((address_space(1))) void*)(B + (size_t)(bn + row) * DIM + k0 + cg * 8),
                (__attribute__((address_space(3))) void*)(Bs + (size_t)(r * 256 + w * 64) * 8),
                16, 0, 0);
        }
    };

    auto compute = [&](int buf) {
        const unsigned short* As = shm + buf * 8192;
        const unsigned short* Bs = As + 4096;
        short8 af[4], bf[4];
        #pragma unroll
        for (int m = 0; m < 4; ++m)
            af[m] = *(const short8*)(As + (wr * 64 + m * 16 + l15) * TBK + kg * 8);
        #pragma unroll
        for (int n = 0; n < 4; ++n)
            bf[n] = *(const short8*)(Bs + (wc * 64 + n * 16 + l15) * TBK + kg * 8);
        #pragma unroll
        for (int m = 0; m < 4; ++m)
            #pragma unroll
            for (int n = 0; n < 4; ++n)
                acc[m][n] = __builtin_amdgcn_mfma_f32_16x16x32_bf16(af[m], bf[n], acc[m][n], 0, 0, 0);
    };

    // prologue: 3 tiles in flight, wait only for the first (vmcnt(8))
    stage(0, 0);
    stage(1, TBK);
    stage(2, 2 * TBK);
    asm volatile("s_waitcnt vmcnt(8)" ::: "memory");
    __builtin_amdgcn_sched_barrier(0);
    __builtin_amdgcn_s_barrier();
    __builtin_amdgcn_sched_barrier(0);

    #pragma unroll
    for (int t = 0; t < KTILES; ++t) {
        const int cur = t % 3;                 // static under full unroll
        compute(cur);
        // ds_reads retired into regs before signaling (rule #18)
        asm volatile("s_waitcnt lgkmcnt(0)" ::: "memory");
        __builtin_amdgcn_sched_barrier(0);
        __builtin_amdgcn_s_barrier();          // all waves done reading buf[cur]
        __builtin_amdgcn_sched_barrier(0);

        if (t + 3 < KTILES) stage(cur, (t + 3) * TBK);   // refill buf[cur]

        if (t + 1 < KTILES) {
            if (t + 3 < KTILES)
                asm volatile("s_waitcnt vmcnt(8)" ::: "memory");  // t+1 done; t+2,t+3 fly
            else if (t + 2 < KTILES)
                asm volatile("s_waitcnt vmcnt(4)" ::: "memory");  // t+1 done; t+2 flies
            else
                asm volatile("s_waitcnt vmcnt(0)" ::: "memory");  // tail
            __builtin_amdgcn_sched_barrier(0);
            __builtin_amdgcn_s_barrier();      // next buf ready for next compute
            __builtin_amdgcn_sched_barrier(0);
        }
    }

    // ---- bias add into acc (regs) ----
    float bv[4];
    #pragma unroll
    for (int n = 0; n < 4; ++n)
        bv[n] = bias[bn + wc * 64 + n * 16 + l15];
    #pragma unroll
    for (int m = 0; m < 4; ++m)
        #pragma unroll
        for (int n = 0; n < 4; ++n)
            #pragma unroll
            for (int r = 0; r < 4; ++r)
                acc[m][n][r] += bv[n];

    // ---- C write via LDS round-trip: 2 passes of 64 rows, stride 136 (16B-aligned)
    // C/D layout: col = lane&15, row = (lane>>4)*4 + reg [m89]
    #pragma unroll
    for (int p = 0; p < 2; ++p) {
        __syncthreads();                 // waves done with shm (K-loop / prev pass)
        if (wr == p) {
            #pragma unroll
            for (int m = 0; m < 4; ++m)
                #pragma unroll
                for (int n = 0; n < 4; ++n)
                    #pragma unroll
                    for (int r = 0; r < 4; ++r) {
                        const int row = m * 16 + kg * 4 + r;        // 0..63
                        const int col = wc * 64 + n * 16 + l15;     // 0..127
                        shm[row * 136 + col] = f32_to_bf16(acc[m][n][r]);
                    }
        }
        __syncthreads();
        #pragma unroll
        for (int i = 0; i < 4; ++i) {
            const int c = tid + 256 * i;            // 0..1023
            const int row = c >> 4, colg = c & 15;
            ushort8v v = *(const ushort8v*)(shm + row * 136 + colg * 8);
            *(ushort8v*)(C + (size_t)(bm + p * 64 + row) * VOCAB + bn + colg * 8) = v;
        }
    }

    // ---- fused per-tile softmax partials over this block's 128 columns ----
    float vmax[4][4];
    #pragma unroll
    for (int m = 0; m < 4; ++m)
        #pragma unroll
        for (int r = 0; r < 4; ++r) {
            float v = fmaxf(fmaxf(acc[m][0][r], acc[m][1][r]),
                            fmaxf(acc[m][2][r], acc[m][3][r]));
            #pragma unroll
            for (int off = 1; off < 16; off <<= 1)
                v = fmaxf(v, __shfl_xor(v, off));
            vmax[m][r] = v;
        }
    if (wc == 0 && l15 == 0)
        #pragma unroll
        for (int m = 0; m < 4; ++m)
            #pragma unroll
            for (int r = 0; r < 4; ++r)
                pmax[wr * 64 + m * 16 + kg * 4 + r] = vmax[m][r];
    __syncthreads();
    if (wc == 1 && l15 == 0)
        #pragma unroll
        for (int m = 0; m < 4; ++m)
            #pragma unroll
            for (int r = 0; r < 4; ++r) {
                const int rl = wr * 64 + m * 16 + kg * 4 + r;
                pmax[rl] = fmaxf(pmax[rl], vmax[m][r]);
            }
    __syncthreads();

    float vsum[4][4];
    #pragma unroll
    for (int m = 0; m < 4; ++m)
        #pragma unroll
        for (int r = 0; r < 4; ++r) {
            const float M = pmax[wr * 64 + m * 16 + kg * 4 + r];
            // exp(x) = exp2(x*log2e): single v_exp_f32 each
            float s = exp2f((acc[m][0][r] - M) * LOG2E) + exp2f((acc[m][1][r] - M) * LOG2E)
                    + exp2f((acc[m][2][r] - M) * LOG2E) + exp2f((acc[m][3][r] - M) * LOG2E);
            #pragma unroll
            for (int off = 1; off < 16; off <<= 1)
                s += __shfl_xor(s, off);
            vsum[m][r] = s;
        }
    if (wc == 0 && l15 == 0)
        #pragma unroll
        for (int m = 0; m < 4; ++m)
            #pragma unroll
            for (int r = 0; r < 4; ++r)
                psum[wr * 64 + m * 16 + kg * 4 + r] = vsum[m][r];
    __syncthreads();
    if (wc == 1 && l15 == 0)
        #pragma unroll
        for (int m = 0; m < 4; ++m)
            #pragma unroll
            for (int r = 0; r < 4; ++r)
                psum[wr * 64 + m * 16 + kg * 4 + r] += vsum[m][r];
    __syncthreads();

    if (tid < TBM) {
        float2 p; p.x = pmax[tid]; p.y = psum[tid];
        partials[(size_t)(bm + tid) * NT + (bn / TBN)] = p;
    }
}

// ---------------- kernel 3: fused pcopy + merge + fixup (one block per row) ------
// Phase 0: pc = sigmoid(hidden[n].Wc + bc) (block reduce).
// Phase 1: reduce NT per-tile partials -> M, SUM; lfv[n] = log((1-pc)/SUM) - M.
// Phase 2: LDS-hash dedup of src ids, emit (index,value) side-list; duplicates
// emit identical bits -> apply is race-free by idempotence.
__global__ __launch_bounds__(256) void fixup_kernel(const float2* __restrict__ partials,
                                                    const unsigned short* __restrict__ C,
                                                    const float* __restrict__ attn,
                                                    const int* __restrict__ src,
                                                    const float* __restrict__ hidden,
                                                    const float* __restrict__ Wc,
                                                    const float* __restrict__ bc,
                                                    float* __restrict__ lfv,
                                                    int* __restrict__ sidx,
                                                    float* __restrict__ sval) {
    const int n = blockIdx.x;
    const int tid = threadIdx.x;
    const int b = n & (BATCH - 1);
    __shared__ float red[256];
    __shared__ float pcn_s;
    __shared__ int   hid[HSZ];
    __shared__ float hacc[HSZ];
    __shared__ short hslot[S_LEN];

    // ---- phase 0: p_copy for this row ----
    float d0 = 0.f;
    if (tid < DIM / 4) {
        float4 a = reinterpret_cast<const float4*>(hidden + (size_t)n * DIM)[tid];
        float4 wv = reinterpret_cast<const float4*>(Wc)[tid];
        d0 = a.x * wv.x + a.y * wv.y + a.z * wv.z + a.w * wv.w;
    }
    red[tid] = d0; __syncthreads();
    for (int s = 128; s > 0; s >>= 1) {
        if (tid < s) red[tid] += red[tid + s];
        __syncthreads();
    }
    if (tid == 0) pcn_s = 1.f / (1.f + expf(-(red[0] + bc[0])));
    __syncthreads();
    const float pcn = pcn_s;
    __syncthreads();

    // ---- phase 1: merge partials ----
    float2 p = {0.f, 0.f};
    float m0 = -INFINITY;
    if (tid < NT) { p = partials[(size_t)n * NT + tid]; m0 = p.x; }
    red[tid] = m0; __syncthreads();
    for (int s = 128; s > 0; s >>= 1) {
        if (tid < s) red[tid] = fmaxf(red[tid], red[tid + s]);
        __syncthreads();
    }
    const float M = red[0];
    __syncthreads();
    float s0 = (tid < NT) ? p.y * exp2f((p.x - M) * LOG2E) : 0.f;
    red[tid] = s0; __syncthreads();
    for (int st = 128; st > 0; st >>= 1) {
        if (tid < st) red[tid] += red[tid + st];
        __syncthreads();
    }
    const float SUM = red[0];
    if (tid == 0) lfv[n] = logf((1.f - pcn) / SUM) - M;

    // ---- phase 2: hash fixup ----
    for (int i = tid; i < HSZ; i += 256) { hid[i] = -1; hacc[i] = 0.f; }
    __syncthreads();

    for (int s = tid; s < S_LEN; s += 256) {
        const int v = src[s * BATCH + b];
        const float a = attn[(size_t)n * S_LEN + s];
        unsigned h = (((unsigned)v) * 2654435761u >> 22) & (HSZ - 1);
        while (true) {
            int old = atomicCAS(&hid[h], -1, v);
            if (old == -1 || old == v) break;
            h = (h + 1) & (HSZ - 1);
        }
        atomicAdd(&hacc[h], a);
        hslot[s] = (short)h;
    }
    __syncthreads();

    const float f = (1.f - pcn) / SUM;

    for (int s = tid; s < S_LEN; s += 256) {
        const int h = hslot[s];
        const int v = hid[h];
        const float c = hacc[h];
        const float l = bf16_to_f32(C[(size_t)n * VOCAB + v]);
        const float prob = exp2f((l - M) * LOG2E) * f + pcn * c;
        sidx[n * S_LEN + s] = n * VOCAB + v;
        sval[n * S_LEN + s] = logf(fmaxf(prob, 1e-20f));
    }
}

// ---------------- kernel 4: scale+log, one block per row (no div, lf once) ------
// out = max(l + lf[n], LOG_CLIP)
__global__ void scalelog_kernel(const unsigned short* __restrict__ Cb,
                                float* __restrict__ out,
                                const float* __restrict__ lfv) {
    const int n = blockIdx.x;
    const float lf = lfv[n];
    const ushort8v* row8 = reinterpret_cast<const ushort8v*>(Cb + (size_t)n * VOCAB);
    float4* out4 = reinterpret_cast<float4*>(out + (size_t)n * VOCAB);
    for (int j = threadIdx.x; j < VOCAB / 8; j += 256) {
        ushort8v raw = row8[j];
        float4 o0, o1;
        o0.x = fmaxf(bf16_to_f32(raw[0]) + lf, LOG_CLIP);
        o0.y = fmaxf(bf16_to_f32(raw[1]) + lf, LOG_CLIP);
        o0.z = fmaxf(bf16_to_f32(raw[2]) + lf, LOG_CLIP);
        o0.w = fmaxf(bf16_to_f32(raw[3]) + lf, LOG_CLIP);
        o1.x = fmaxf(bf16_to_f32(raw[4]) + lf, LOG_CLIP);
        o1.y = fmaxf(bf16_to_f32(raw[5]) + lf, LOG_CLIP);
        o1.z = fmaxf(bf16_to_f32(raw[6]) + lf, LOG_CLIP);
        o1.w = fmaxf(bf16_to_f32(raw[7]) + lf, LOG_CLIP);
        out4[j * 2]     = o0;
        out4[j * 2 + 1] = o1;
    }
}

// ---------------- kernel 5: apply side-list (duplicates write identical bits) -----
__global__ void apply_kernel(const int* __restrict__ sidx,
                             const float* __restrict__ sval,
                             float* __restrict__ out) {
    const int i = blockIdx.x * blockDim.x + threadIdx.x;
    if (i >= N_ROWS * S_LEN) return;
    out[sidx[i]] = sval[i];
}

// ================= f32 fallback path (ws too small) =================
#define BM 64
#define BN 64
#define BK 16

__global__ void pcopy_kernel(const float* __restrict__ hidden,
                             const float* __restrict__ Wc,
                             const float* __restrict__ bc,
                             float* __restrict__ pc) {
    int n = blockIdx.x;
    int lane = threadIdx.x;
    const float4* h4 = reinterpret_cast<const float4*>(hidden + (size_t)n * DIM);
    const float4* w4 = reinterpret_cast<const float4*>(Wc);
    float acc = 0.f;
    #pragma unroll
    for (int i = lane; i < DIM / 4; i += 64) {
        float4 a = h4[i], b = w4[i];
        acc += a.x * b.x + a.y * b.y + a.z * b.z + a.w * b.w;
    }
    for (int off = 32; off > 0; off >>= 1)
        acc += __shfl_down(acc, off);
    if (lane == 0) {
        float z = acc + bc[0];
        pc[n] = 1.f / (1.f + expf(-z));
    }
}

__global__ __launch_bounds__(256) void gemm_kernel(const float* __restrict__ A,
                                                   const float* __restrict__ B,
                                                   const float* __restrict__ bias,
                                                   float* __restrict__ C) {
    __shared__ float As[BK][BM + 4];
    __shared__ float Bs[BK][BN + 4];

    const int bm = blockIdx.y * BM;
    const int bn = blockIdx.x * BN;
    const int tid = threadIdx.x;
    const int lr = tid >> 2;
    const int lk = (tid & 3) * 4;
    const int tm = (tid >> 4) * 4;
    const int tn = (tid & 15) * 4;

    float acc[4][4] = {};

    for (int k0 = 0; k0 < DIM; k0 += BK) {
        float4 a  = *reinterpret_cast<const float4*>(A + (size_t)(bm + lr) * DIM + k0 + lk);
        float4 bv = *reinterpret_cast<const float4*>(B + (size_t)(bn + lr) * DIM + k0 + lk);
        As[lk + 0][lr] = a.x;  As[lk + 1][lr] = a.y;  As[lk + 2][lr] = a.z;  As[lk + 3][lr] = a.w;
        Bs[lk + 0][lr] = bv.x; Bs[lk + 1][lr] = bv.y; Bs[lk + 2][lr] = bv.z; Bs[lk + 3][lr] = bv.w;
        __syncthreads();
        #pragma unroll
        for (int kk = 0; kk < BK; ++kk) {
            float4 av = *reinterpret_cast<const float4*>(&As[kk][tm]);
            float4 bw = *reinterpret_cast<const float4*>(&Bs[kk][tn]);
            float am[4] = {av.x, av.y, av.z, av.w};
            float bb[4] = {bw.x, bw.y, bw.z, bw.w};
            #pragma unroll
            for (int i = 0; i < 4; ++i)
                #pragma unroll
                for (int j = 0; j < 4; ++j)
                    acc[i][j] = fmaf(am[i], bb[j], acc[i][j]);
        }
        __syncthreads();
    }

    #pragma unroll
    for (int i = 0; i < 4; ++i) {
        float4 v;
        v.x = acc[i][0] + bias[bn + tn + 0];
        v.y = acc[i][1] + bias[bn + tn + 1];
        v.z = acc[i][2] + bias[bn + tn + 2];
        v.w = acc[i][3] + bias[bn + tn + 3];
        *reinterpret_cast<float4*>(C + (size_t)(bm + tm + i) * VOCAB + bn + tn) = v;
    }
}

__global__ __launch_bounds__(256) void rowstat_kernel(const float* __restrict__ logits,
                                                      float* __restrict__ rowmax,
                                                      float* __restrict__ rowsum) {
    const int n = blockIdx.x;
    const int tid = threadIdx.x;
    const float* row = logits + (size_t)n * VOCAB;
    __shared__ float red[256];

    float m = -INFINITY;
    for (int i = tid; i < VOCAB; i += 256) m = fmaxf(m, row[i]);
    red[tid] = m; __syncthreads();
    for (int s = 128; s > 0; s >>= 1) {
        if (tid < s) red[tid] = fmaxf(red[tid], red[tid + s]);
        __syncthreads();
    }
    m = red[0];
    __syncthreads();

    float sum = 0.f;
    for (int i = tid; i < VOCAB; i += 256) sum += expf(row[i] - m);
    red[tid] = sum; __syncthreads();
    for (int s = 128; s > 0; s >>= 1) {
        if (tid < s) red[tid] += red[tid + s];
        __syncthreads();
    }
    if (tid == 0) { rowmax[n] = m; rowsum[n] = red[0]; }
}

__global__ void scale_kernel(float* __restrict__ out,
                             const float* __restrict__ pc,
                             const float* __restrict__ rowmax,
                             const float* __restrict__ rowsum) {
    const unsigned total4 = (unsigned)N_ROWS * (VOCAB / 4);
    for (unsigned idx = blockIdx.x * blockDim.x + threadIdx.x; idx < total4;
         idx += gridDim.x * blockDim.x) {
        const unsigned n = idx / (VOCAB / 4);
        const float m = rowmax[n];
        const float f = (1.f - pc[n]) / rowsum[n];
        float4 v = reinterpret_cast<float4*>(out)[idx];
        v.x = expf(v.x - m) * f;
        v.y = expf(v.y - m) * f;
        v.z = expf(v.z - m) * f;
        v.w = expf(v.w - m) * f;
        reinterpret_cast<float4*>(out)[idx] = v;
    }
}

__global__ void scatter_kernel(float* __restrict__ out,
                               const float* __restrict__ attn,
                               const int* __restrict__ src,
                               const float* __restrict__ pc) {
    const int tid = blockIdx.x * blockDim.x + threadIdx.x;
    if (tid >= N_ROWS * S_LEN) return;
    const int n = tid / S_LEN;
    const int s = tid % S_LEN;
    const int b = n % BATCH;
    const int v = src[s * BATCH + b];
    atomicAdd(out + (size_t)n * VOCAB + v, attn[(size_t)n * S_LEN + s] * pc[n]);
}

__global__ void log_kernel(float* __restrict__ out) {
    const unsigned total4 = (unsigned)N_ROWS * (VOCAB / 4);
    for (unsigned idx = blockIdx.x * blockDim.x + threadIdx.x; idx < total4;
         idx += gridDim.x * blockDim.x) {
        float4 v = reinterpret_cast<float4*>(out)[idx];
        v.x = logf(fmaxf(v.x, 1e-20f));
        v.y = logf(fmaxf(v.y, 1e-20f));
        v.z = logf(fmaxf(v.z, 1e-20f));
        v.w = logf(fmaxf(v.w, 1e-20f));
        reinterpret_cast<float4*>(out)[idx] = v;
    }
}

extern "C" void kernel_launch(void* const* d_in, const int* in_sizes, int n_in,
                              void* d_out, int out_size, void* d_ws, size_t ws_size,
                              hipStream_t stream) {
    const float* hidden = (const float*)d_in[0];   // [N, D]
    const float* attn   = (const float*)d_in[1];   // [N, S]
    const int*   src    = (const int*)d_in[2];     // [S, B, 1] (int32 on device)
    const float* W      = (const float*)d_in[3];   // [V, D]
    const float* bias   = (const float*)d_in[4];   // [V]
    const float* Wc     = (const float*)d_in[5];   // [1, D]
    const float* bc     = (const float*)d_in[6];   // [1]
    float* out = (float*)d_out;                    // [N, V]

    // workspace layout (256B-aligned slots)
    const size_t wb_bytes   = (size_t)VOCAB * DIM * 2;          //  32.8 MB
    const size_t hb_bytes   = (size_t)N_ROWS * DIM * 2;         //   2.1 MB
    const size_t cb_bytes   = (size_t)N_ROWS * VOCAB * 2;       // 131.1 MB (bf16 logits)
    const size_t vec_bytes  = (size_t)N_ROWS * 4;               //   8 KB each
    const size_t part_bytes = (size_t)N_ROWS * NT * 8;          //   4.1 MB
    const size_t side_bytes = (size_t)N_ROWS * S_LEN * 4;       //   3.3 MB each

    size_t off = 0;
    auto alloc = [&](size_t bytes) { size_t o = off; off = (off + bytes + 255) & ~(size_t)255; return o; };
    char* ws = (char*)d_ws;
    const size_t o_wb   = alloc(wb_bytes);
    const size_t o_hb   = alloc(hb_bytes);
    const size_t o_cb   = alloc(cb_bytes);
    const size_t o_pc   = alloc(vec_bytes);
    const size_t o_lf   = alloc(vec_bytes);
    const size_t o_sum  = alloc(vec_bytes);
    const size_t o_part = alloc(part_bytes);
    const size_t o_sidx = alloc(side_bytes);
    const size_t o_sval = alloc(side_bytes);
    const size_t need = off;

    if (ws_size >= need) {
        unsigned short* Wb = (unsigned short*)(ws + o_wb);
        unsigned short* Hb = (unsigned short*)(ws + o_hb);
        unsigned short* Cb = (unsigned short*)(ws + o_cb);
        float*  lfv      = (float*)(ws + o_lf);
        float2* partials = (float2*)(ws + o_part);
        int*    sidx     = (int*)(ws + o_sidx);
        float*  sval     = (float*)(ws + o_sval);

        cast2_bf16_kernel<<<2048, 256, 0, stream>>>(W, Wb, (unsigned)(VOCAB * DIM / 4),
                                                    hidden, Hb, (unsigned)(N_ROWS * DIM / 4));

        const int nwg = (VOCAB / TBN) * (N_ROWS / TBM);   // 4000
        gemm_mfma_kernel<<<nwg, 256, 0, stream>>>(Hb, Wb, bias, Cb, partials);

        fixup_kernel<<<N_ROWS, 256, 0, stream>>>(partials, Cb, attn, src,
                                                 hidden, Wc, bc, lfv, sidx, sval);
        scalelog_kernel<<<N_ROWS, 256, 0, stream>>>(Cb, out, lfv);
        apply_kernel<<<(N_ROWS * S_LEN + 255) / 256, 256, 0, stream>>>(sidx, sval, out);
    } else {
        float* pc     = (float*)(ws + o_pc);
        float* rowmax = pc + N_ROWS;
        float* rowsum = rowmax + N_ROWS;

        pcopy_kernel<<<N_ROWS, 64, 0, stream>>>(hidden, Wc, bc, pc);
        dim3 ggrid(VOCAB / BN, N_ROWS / BM);
        gemm_kernel<<<ggrid, 256, 0, stream>>>(hidden, W, bias, out);
        rowstat_kernel<<<N_ROWS, 256, 0, stream>>>(out, rowmax, rowsum);
        scale_kernel<<<4096, 256, 0, stream>>>(out, pc, rowmax, rowsum);
        scatter_kernel<<<(N_ROWS * S_LEN + 255) / 256, 256, 0, stream>>>(out, attn, src, pc);
        log_kernel<<<4096, 256, 0, stream>>>(out);
    }
}

// Round 14
// 297.639 us; speedup vs baseline: 1.0499x; 1.0499x over previous
//
#include <hip/hip_runtime.h>
#include <math.h>
#include <stdint.h>

#define N_ROWS 2048
#define DIM    512
#define VOCAB  32000
#define S_LEN  400
#define BATCH  32
#define NT     (VOCAB / 128)      // 250 N-tiles
#define LOG_CLIP -46.0517018598809136f   // log(1e-20)
#define LOG2E  1.4426950408889634f
#define HSZ    1024               // fixup LDS hash slots (>= 2*S_LEN, pow2)

typedef __attribute__((ext_vector_type(8))) short short8;
typedef __attribute__((ext_vector_type(8))) unsigned short ushort8v;
typedef __attribute__((ext_vector_type(4))) float floatx4;

__device__ inline unsigned short f32_to_bf16(float f) {
    union { float f; unsigned u; } v; v.f = f;
    unsigned u = v.u;
    return (unsigned short)((u + 0x7FFFu + ((u >> 16) & 1u)) >> 16);   // RNE
}
__device__ inline float bf16_to_f32(unsigned short h) {
    union { unsigned u; float f; } v; v.u = ((unsigned)h) << 16;
    return v.f;
}

// ---------------- kernel 0: fused f32 -> bf16 cast for W and hidden ----------------
__global__ void cast2_bf16_kernel(const float* __restrict__ srcW,
                                  unsigned short* __restrict__ dstW, unsigned n4w,
                                  const float* __restrict__ srcH,
                                  unsigned short* __restrict__ dstH, unsigned n4h) {
    const unsigned total = n4w + n4h;
    for (unsigned i = blockIdx.x * blockDim.x + threadIdx.x; i < total;
         i += gridDim.x * blockDim.x) {
        const float4* s = (i < n4w) ? reinterpret_cast<const float4*>(srcW) + i
                                    : reinterpret_cast<const float4*>(srcH) + (i - n4w);
        ushort4* d = (i < n4w) ? reinterpret_cast<ushort4*>(dstW) + i
                               : reinterpret_cast<ushort4*>(dstH) + (i - n4w);
        float4 v = *s;
        ushort4 o;
        o.x = f32_to_bf16(v.x); o.y = f32_to_bf16(v.y);
        o.z = f32_to_bf16(v.z); o.w = f32_to_bf16(v.w);
        *d = o;
    }
}

// ---------------- kernel 1: p_copy = sigmoid(hidden @ Wc^T + bc) ----------------
__global__ void pcopy_kernel(const float* __restrict__ hidden,
                             const float* __restrict__ Wc,
                             const float* __restrict__ bc,
                             float* __restrict__ pc) {
    int n = blockIdx.x;
    int lane = threadIdx.x;                     // 64 threads = 1 wave
    const float4* h4 = reinterpret_cast<const float4*>(hidden + (size_t)n * DIM);
    const float4* w4 = reinterpret_cast<const float4*>(Wc);
    float acc = 0.f;
    #pragma unroll
    for (int i = lane; i < DIM / 4; i += 64) {
        float4 a = h4[i], b = w4[i];
        acc += a.x * b.x + a.y * b.y + a.z * b.z + a.w * b.w;
    }
    for (int off = 32; off > 0; off >>= 1)
        acc += __shfl_down(acc, off);
    if (lane == 0) {
        float z = acc + bc[0];
        pc[n] = 1.f / (1.f + expf(-z));
    }
}

// ---------------- kernel 2: bf16 MFMA GEMM, counted-vmcnt TRIPLE-buffer + T2 ----
// TBK=32, 3 LDS buffers, counted vmcnt (never 0 in steady state).
// T2 LDS swizzle (both-sides, rule #21): logical (row,kg) lives at slot
// kg^((row>>1)&3); LDS dest stays LINEAR (gload_lds), global SOURCE pre-swizzled,
// ds_read uses the swizzled slot. Bank-group = 4*(row&1) | (kg^((row>>1)&3))
// -> uniform 8 accesses/group across the wave = b128 minimum = conflict-free.
#define TBM 128
#define TBN 128
#define TBK 32
#define KTILES (DIM / TBK)        // 16

__global__ __launch_bounds__(256) void gemm_mfma_kernel(
        const unsigned short* __restrict__ A,
        const unsigned short* __restrict__ B,
        const float* __restrict__ bias,
        unsigned short* __restrict__ C,          // bf16 logits
        float2* __restrict__ partials) {
    // 3 bufs x (A 4096 | B 4096) ushorts = 48 KB; epilogue reuses [64][136] (8696)
    __shared__ unsigned short shm[24576];
    __shared__ float pmax[TBM];
    __shared__ float psum[TBM];

    const int tid  = threadIdx.x;
    const int lane = tid & 63;
    const int w    = tid >> 6;          // wave 0..3
    const int wr   = w >> 1, wc = w & 1;

    // chunked XCD swizzle (nwg=4000, 4000%8==0 -> bijective), then by-fastest:
    // 16 consecutive swz ids on one XCD share the same B panel.
    const unsigned nwg  = (unsigned)(VOCAB / TBN) * (N_ROWS / TBM);   // 4000
    const unsigned orig = blockIdx.x;
    const unsigned swz  = (orig & 7u) * (nwg / 8u) + (orig >> 3);
    const int bm = (int)(swz & 15u) * TBM;      // N_ROWS/TBM = 16
    const int bn = (int)(swz >> 4)  * TBN;      // 0..249

    const int l15 = lane & 15;
    const int kg  = lane >> 4;          // 0..3

    floatx4 acc[4][4] = {};

    // stage one 128x32 A-tile + B-tile into buf: LDS linear, global src pre-swizzled.
    // slot s holds logical kg = (s&3) ^ ((row>>1)&3), row = s>>2.
    auto stage = [&](int buf, int k0) {
        unsigned short* As = shm + buf * 8192;
        unsigned short* Bs = As + 4096;
        #pragma unroll
        for (int r = 0; r < 2; ++r) {
            const int chunk = r * 256 + w * 64 + lane;       // 16B slot 0..511
            const int row = chunk >> 2;
            const int cg  = (chunk & 3) ^ ((chunk >> 3) & 3);   // pre-swizzled source kg
            __builtin_amdgcn_global_load_lds(
                (const __attribute__((address_space(1))) void*)(A + (size_t)(bm + row) * DIM + k0 + cg * 8),
                (__attribute__((address_space(3))) void*)(As + (size_t)(r * 256 + w * 64) * 8),
                16, 0, 0);
        }
        #pragma unroll
        for (int r = 0; r < 2; ++r) {
            const int chunk = r * 256 + w * 64 + lane;
            const int row = chunk >> 2;
            const int cg  = (chunk & 3) ^ ((chunk >> 3) & 3);
            __builtin_amdgcn_global_load_lds(
                (const __attribute__((address_space(1))) void*)(B + (size_t)(bn + row) * DIM + k0 + cg * 8),
                (__attribute__((address_space(3))) void*)(Bs + (size_t)(r * 256 + w * 64) * 8),
                16, 0, 0);
        }
    };

    auto compute = [&](int buf) {
        const unsigned short* As = shm + buf * 8192;
        const unsigned short* Bs = As + 4096;
        short8 af[4], bf[4];
        #pragma unroll
        for (int m = 0; m < 4; ++m) {
            const int row = wr * 64 + m * 16 + l15;
            const int ks  = kg ^ ((row >> 1) & 3);           // swizzled slot
            af[m] = *(const short8*)(As + row * TBK + ks * 8);
        }
        #pragma unroll
        for (int n = 0; n < 4; ++n) {
            const int row = wc * 64 + n * 16 + l15;
            const int ks  = kg ^ ((row >> 1) & 3);
            bf[n] = *(const short8*)(Bs + row * TBK + ks * 8);
        }
        #pragma unroll
        for (int m = 0; m < 4; ++m)
            #pragma unroll
            for (int n = 0; n < 4; ++n)
                acc[m][n] = __builtin_amdgcn_mfma_f32_16x16x32_bf16(af[m], bf[n], acc[m][n], 0, 0, 0);
    };

    // prologue: 3 tiles in flight, wait only for the first (vmcnt(8))
    stage(0, 0);
    stage(1, TBK);
    stage(2, 2 * TBK);
    asm volatile("s_waitcnt vmcnt(8)" ::: "memory");
    __builtin_amdgcn_sched_barrier(0);
    __builtin_amdgcn_s_barrier();
    __builtin_amdgcn_sched_barrier(0);

    #pragma unroll
    for (int t = 0; t < KTILES; ++t) {
        const int cur = t % 3;                 // static under full unroll
        compute(cur);
        // ds_reads retired into regs before signaling (rule #18)
        asm volatile("s_waitcnt lgkmcnt(0)" ::: "memory");
        __builtin_amdgcn_sched_barrier(0);
        __builtin_amdgcn_s_barrier();          // all waves done reading buf[cur]
        __builtin_amdgcn_sched_barrier(0);

        if (t + 3 < KTILES) stage(cur, (t + 3) * TBK);   // refill buf[cur]

        if (t + 1 < KTILES) {
            if (t + 3 < KTILES)
                asm volatile("s_waitcnt vmcnt(8)" ::: "memory");  // t+1 done; t+2,t+3 fly
            else if (t + 2 < KTILES)
                asm volatile("s_waitcnt vmcnt(4)" ::: "memory");  // t+1 done; t+2 flies
            else
                asm volatile("s_waitcnt vmcnt(0)" ::: "memory");  // tail
            __builtin_amdgcn_sched_barrier(0);
            __builtin_amdgcn_s_barrier();      // next buf ready for next compute
            __builtin_amdgcn_sched_barrier(0);
        }
    }

    // ---- bias add into acc (regs) ----
    float bv[4];
    #pragma unroll
    for (int n = 0; n < 4; ++n)
        bv[n] = bias[bn + wc * 64 + n * 16 + l15];
    #pragma unroll
    for (int m = 0; m < 4; ++m)
        #pragma unroll
        for (int n = 0; n < 4; ++n)
            #pragma unroll
            for (int r = 0; r < 4; ++r)
                acc[m][n][r] += bv[n];

    // ---- C write via LDS round-trip: 2 passes of 64 rows, stride 136 (16B-aligned)
    // C/D layout: col = lane&15, row = (lane>>4)*4 + reg [m89]
    #pragma unroll
    for (int p = 0; p < 2; ++p) {
        __syncthreads();                 // waves done with shm (K-loop / prev pass)
        if (wr == p) {
            #pragma unroll
            for (int m = 0; m < 4; ++m)
                #pragma unroll
                for (int n = 0; n < 4; ++n)
                    #pragma unroll
                    for (int r = 0; r < 4; ++r) {
                        const int row = m * 16 + kg * 4 + r;        // 0..63
                        const int col = wc * 64 + n * 16 + l15;     // 0..127
                        shm[row * 136 + col] = f32_to_bf16(acc[m][n][r]);
                    }
        }
        __syncthreads();
        #pragma unroll
        for (int i = 0; i < 4; ++i) {
            const int c = tid + 256 * i;            // 0..1023
            const int row = c >> 4, colg = c & 15;
            ushort8v v = *(const ushort8v*)(shm + row * 136 + colg * 8);
            *(ushort8v*)(C + (size_t)(bm + p * 64 + row) * VOCAB + bn + colg * 8) = v;
        }
    }

    // ---- fused per-tile softmax partials over this block's 128 columns ----
    float vmax[4][4];
    #pragma unroll
    for (int m = 0; m < 4; ++m)
        #pragma unroll
        for (int r = 0; r < 4; ++r) {
            float v = fmaxf(fmaxf(acc[m][0][r], acc[m][1][r]),
                            fmaxf(acc[m][2][r], acc[m][3][r]));
            #pragma unroll
            for (int off = 1; off < 16; off <<= 1)
                v = fmaxf(v, __shfl_xor(v, off));
            vmax[m][r] = v;
        }
    if (wc == 0 && l15 == 0)
        #pragma unroll
        for (int m = 0; m < 4; ++m)
            #pragma unroll
            for (int r = 0; r < 4; ++r)
                pmax[wr * 64 + m * 16 + kg * 4 + r] = vmax[m][r];
    __syncthreads();
    if (wc == 1 && l15 == 0)
        #pragma unroll
        for (int m = 0; m < 4; ++m)
            #pragma unroll
            for (int r = 0; r < 4; ++r) {
                const int rl = wr * 64 + m * 16 + kg * 4 + r;
                pmax[rl] = fmaxf(pmax[rl], vmax[m][r]);
            }
    __syncthreads();

    float vsum[4][4];
    #pragma unroll
    for (int m = 0; m < 4; ++m)
        #pragma unroll
        for (int r = 0; r < 4; ++r) {
            const float M = pmax[wr * 64 + m * 16 + kg * 4 + r];
            // exp(x) = exp2(x*log2e): single v_exp_f32 each
            float s = exp2f((acc[m][0][r] - M) * LOG2E) + exp2f((acc[m][1][r] - M) * LOG2E)
                    + exp2f((acc[m][2][r] - M) * LOG2E) + exp2f((acc[m][3][r] - M) * LOG2E);
            #pragma unroll
            for (int off = 1; off < 16; off <<= 1)
                s += __shfl_xor(s, off);
            vsum[m][r] = s;
        }
    if (wc == 0 && l15 == 0)
        #pragma unroll
        for (int m = 0; m < 4; ++m)
            #pragma unroll
            for (int r = 0; r < 4; ++r)
                psum[wr * 64 + m * 16 + kg * 4 + r] = vsum[m][r];
    __syncthreads();
    if (wc == 1 && l15 == 0)
        #pragma unroll
        for (int m = 0; m < 4; ++m)
            #pragma unroll
            for (int r = 0; r < 4; ++r)
                psum[wr * 64 + m * 16 + kg * 4 + r] += vsum[m][r];
    __syncthreads();

    if (tid < TBM) {
        float2 p; p.x = pmax[tid]; p.y = psum[tid];
        partials[(size_t)(bm + tid) * NT + (bn / TBN)] = p;
    }
}

// ---------------- kernel 3: fused merge + fixup (one block per row) --------------
// Also precomputes lfv[n] = log((1-pc)/SUM) - M so scalelog is a pure fmax stream.
__global__ __launch_bounds__(256) void fixup_kernel(const float2* __restrict__ partials,
                                                    const unsigned short* __restrict__ C,
                                                    const float* __restrict__ attn,
                                                    const int* __restrict__ src,
                                                    const float* __restrict__ pc,
                                                    float* __restrict__ lfv,
                                                    int* __restrict__ sidx,
                                                    float* __restrict__ sval) {
    const int n = blockIdx.x;
    const int tid = threadIdx.x;
    const int b = n & (BATCH - 1);
    __shared__ float red[256];
    __shared__ int   hid[HSZ];
    __shared__ float hacc[HSZ];
    __shared__ short hslot[S_LEN];

    // ---- phase 1: merge partials ----
    float2 p = {0.f, 0.f};
    float m0 = -INFINITY;
    if (tid < NT) { p = partials[(size_t)n * NT + tid]; m0 = p.x; }
    red[tid] = m0; __syncthreads();
    for (int s = 128; s > 0; s >>= 1) {
        if (tid < s) red[tid] = fmaxf(red[tid], red[tid + s]);
        __syncthreads();
    }
    const float M = red[0];
    __syncthreads();
    float s0 = (tid < NT) ? p.y * exp2f((p.x - M) * LOG2E) : 0.f;
    red[tid] = s0; __syncthreads();
    for (int st = 128; st > 0; st >>= 1) {
        if (tid < st) red[tid] += red[tid + st];
        __syncthreads();
    }
    const float SUM = red[0];
    const float pcn = pc[n];
    if (tid == 0) lfv[n] = logf((1.f - pcn) / SUM) - M;

    // ---- phase 2: hash fixup ----
    for (int i = tid; i < HSZ; i += 256) { hid[i] = -1; hacc[i] = 0.f; }
    __syncthreads();

    for (int s = tid; s < S_LEN; s += 256) {
        const int v = src[s * BATCH + b];
        const float a = attn[(size_t)n * S_LEN + s];
        unsigned h = (((unsigned)v) * 2654435761u >> 22) & (HSZ - 1);
        while (true) {
            int old = atomicCAS(&hid[h], -1, v);
            if (old == -1 || old == v) break;
            h = (h + 1) & (HSZ - 1);
        }
        atomicAdd(&hacc[h], a);
        hslot[s] = (short)h;
    }
    __syncthreads();

    const float f = (1.f - pcn) / SUM;

    for (int s = tid; s < S_LEN; s += 256) {
        const int h = hslot[s];
        const int v = hid[h];
        const float c = hacc[h];
        const float l = bf16_to_f32(C[(size_t)n * VOCAB + v]);
        const float prob = exp2f((l - M) * LOG2E) * f + pcn * c;
        sidx[n * S_LEN + s] = n * VOCAB + v;
        sval[n * S_LEN + s] = logf(fmaxf(prob, 1e-20f));
    }
}

// ---------------- kernel 4: fused scale+log: bf16 logits -> f32 log-probs --------
// out = max(l + lf[n], LOG_CLIP) ; lf precomputed in fixup -> pure fmax stream.
__global__ void scalelog_kernel(const unsigned short* __restrict__ Cb,
                                float* __restrict__ out,
                                const float* __restrict__ lfv) {
    const unsigned total8 = (unsigned)N_ROWS * (VOCAB / 8);
    for (unsigned idx = blockIdx.x * blockDim.x + threadIdx.x; idx < total8;
         idx += gridDim.x * blockDim.x) {
        const unsigned n = idx / (VOCAB / 8);
        const float lf = lfv[n];
        ushort8v raw = reinterpret_cast<const ushort8v*>(Cb)[idx];
        float4 o0, o1;
        o0.x = fmaxf(bf16_to_f32(raw[0]) + lf, LOG_CLIP);
        o0.y = fmaxf(bf16_to_f32(raw[1]) + lf, LOG_CLIP);
        o0.z = fmaxf(bf16_to_f32(raw[2]) + lf, LOG_CLIP);
        o0.w = fmaxf(bf16_to_f32(raw[3]) + lf, LOG_CLIP);
        o1.x = fmaxf(bf16_to_f32(raw[4]) + lf, LOG_CLIP);
        o1.y = fmaxf(bf16_to_f32(raw[5]) + lf, LOG_CLIP);
        o1.z = fmaxf(bf16_to_f32(raw[6]) + lf, LOG_CLIP);
        o1.w = fmaxf(bf16_to_f32(raw[7]) + lf, LOG_CLIP);
        reinterpret_cast<float4*>(out)[idx * 2]     = o0;
        reinterpret_cast<float4*>(out)[idx * 2 + 1] = o1;
    }
}

// ---------------- kernel 5: apply side-list (duplicates write identical bits) -----
__global__ void apply_kernel(const int* __restrict__ sidx,
                             const float* __restrict__ sval,
                             float* __restrict__ out) {
    const int i = blockIdx.x * blockDim.x + threadIdx.x;
    if (i >= N_ROWS * S_LEN) return;
    out[sidx[i]] = sval[i];
}

// ================= f32 fallback path (ws too small) =================
#define BM 64
#define BN 64
#define BK 16

__global__ __launch_bounds__(256) void gemm_kernel(const float* __restrict__ A,
                                                   const float* __restrict__ B,
                                                   const float* __restrict__ bias,
                                                   float* __restrict__ C) {
    __shared__ float As[BK][BM + 4];
    __shared__ float Bs[BK][BN + 4];

    const int bm = blockIdx.y * BM;
    const int bn = blockIdx.x * BN;
    const int tid = threadIdx.x;
    const int lr = tid >> 2;
    const int lk = (tid & 3) * 4;
    const int tm = (tid >> 4) * 4;
    const int tn = (tid & 15) * 4;

    float acc[4][4] = {};

    for (int k0 = 0; k0 < DIM; k0 += BK) {
        float4 a  = *reinterpret_cast<const float4*>(A + (size_t)(bm + lr) * DIM + k0 + lk);
        float4 bv = *reinterpret_cast<const float4*>(B + (size_t)(bn + lr) * DIM + k0 + lk);
        As[lk + 0][lr] = a.x;  As[lk + 1][lr] = a.y;  As[lk + 2][lr] = a.z;  As[lk + 3][lr] = a.w;
        Bs[lk + 0][lr] = bv.x; Bs[lk + 1][lr] = bv.y; Bs[lk + 2][lr] = bv.z; Bs[lk + 3][lr] = bv.w;
        __syncthreads();
        #pragma unroll
        for (int kk = 0; kk < BK; ++kk) {
            float4 av = *reinterpret_cast<const float4*>(&As[kk][tm]);
            float4 bw = *reinterpret_cast<const float4*>(&Bs[kk][tn]);
            float am[4] = {av.x, av.y, av.z, av.w};
            float bb[4] = {bw.x, bw.y, bw.z, bw.w};
            #pragma unroll
            for (int i = 0; i < 4; ++i)
                #pragma unroll
                for (int j = 0; j < 4; ++j)
                    acc[i][j] = fmaf(am[i], bb[j], acc[i][j]);
        }
        __syncthreads();
    }

    #pragma unroll
    for (int i = 0; i < 4; ++i) {
        float4 v;
        v.x = acc[i][0] + bias[bn + tn + 0];
        v.y = acc[i][1] + bias[bn + tn + 1];
        v.z = acc[i][2] + bias[bn + tn + 2];
        v.w = acc[i][3] + bias[bn + tn + 3];
        *reinterpret_cast<float4*>(C + (size_t)(bm + tm + i) * VOCAB + bn + tn) = v;
    }
}

__global__ void pcopy_fb_kernel(const float* __restrict__ hidden,
                                const float* __restrict__ Wc,
                                const float* __restrict__ bc,
                                float* __restrict__ pc) {
    int n = blockIdx.x;
    int lane = threadIdx.x;
    const float4* h4 = reinterpret_cast<const float4*>(hidden + (size_t)n * DIM);
    const float4* w4 = reinterpret_cast<const float4*>(Wc);
    float acc = 0.f;
    #pragma unroll
    for (int i = lane; i < DIM / 4; i += 64) {
        float4 a = h4[i], b = w4[i];
        acc += a.x * b.x + a.y * b.y + a.z * b.z + a.w * b.w;
    }
    for (int off = 32; off > 0; off >>= 1)
        acc += __shfl_down(acc, off);
    if (lane == 0) {
        float z = acc + bc[0];
        pc[n] = 1.f / (1.f + expf(-z));
    }
}

__global__ __launch_bounds__(256) void rowstat_kernel(const float* __restrict__ logits,
                                                      float* __restrict__ rowmax,
                                                      float* __restrict__ rowsum) {
    const int n = blockIdx.x;
    const int tid = threadIdx.x;
    const float* row = logits + (size_t)n * VOCAB;
    __shared__ float red[256];

    float m = -INFINITY;
    for (int i = tid; i < VOCAB; i += 256) m = fmaxf(m, row[i]);
    red[tid] = m; __syncthreads();
    for (int s = 128; s > 0; s >>= 1) {
        if (tid < s) red[tid] = fmaxf(red[tid], red[tid + s]);
        __syncthreads();
    }
    m = red[0];
    __syncthreads();

    float sum = 0.f;
    for (int i = tid; i < VOCAB; i += 256) sum += expf(row[i] - m);
    red[tid] = sum; __syncthreads();
    for (int s = 128; s > 0; s >>= 1) {
        if (tid < s) red[tid] += red[tid + s];
        __syncthreads();
    }
    if (tid == 0) { rowmax[n] = m; rowsum[n] = red[0]; }
}

__global__ void scale_kernel(float* __restrict__ out,
                             const float* __restrict__ pc,
                             const float* __restrict__ rowmax,
                             const float* __restrict__ rowsum) {
    const unsigned total4 = (unsigned)N_ROWS * (VOCAB / 4);
    for (unsigned idx = blockIdx.x * blockDim.x + threadIdx.x; idx < total4;
         idx += gridDim.x * blockDim.x) {
        const unsigned n = idx / (VOCAB / 4);
        const float m = rowmax[n];
        const float f = (1.f - pc[n]) / rowsum[n];
        float4 v = reinterpret_cast<float4*>(out)[idx];
        v.x = expf(v.x - m) * f;
        v.y = expf(v.y - m) * f;
        v.z = expf(v.z - m) * f;
        v.w = expf(v.w - m) * f;
        reinterpret_cast<float4*>(out)[idx] = v;
    }
}

__global__ void scatter_kernel(float* __restrict__ out,
                               const float* __restrict__ attn,
                               const int* __restrict__ src,
                               const float* __restrict__ pc) {
    const int tid = blockIdx.x * blockDim.x + threadIdx.x;
    if (tid >= N_ROWS * S_LEN) return;
    const int n = tid / S_LEN;
    const int s = tid % S_LEN;
    const int b = n % BATCH;
    const int v = src[s * BATCH + b];
    atomicAdd(out + (size_t)n * VOCAB + v, attn[(size_t)n * S_LEN + s] * pc[n]);
}

__global__ void log_kernel(float* __restrict__ out) {
    const unsigned total4 = (unsigned)N_ROWS * (VOCAB / 4);
    for (unsigned idx = blockIdx.x * blockDim.x + threadIdx.x; idx < total4;
         idx += gridDim.x * blockDim.x) {
        float4 v = reinterpret_cast<float4*>(out)[idx];
        v.x = logf(fmaxf(v.x, 1e-20f));
        v.y = logf(fmaxf(v.y, 1e-20f));
        v.z = logf(fmaxf(v.z, 1e-20f));
        v.w = logf(fmaxf(v.w, 1e-20f));
        reinterpret_cast<float4*>(out)[idx] = v;
    }
}

extern "C" void kernel_launch(void* const* d_in, const int* in_sizes, int n_in,
                              void* d_out, int out_size, void* d_ws, size_t ws_size,
                              hipStream_t stream) {
    const float* hidden = (const float*)d_in[0];   // [N, D]
    const float* attn   = (const float*)d_in[1];   // [N, S]
    const int*   src    = (const int*)d_in[2];     // [S, B, 1] (int32 on device)
    const float* W      = (const float*)d_in[3];   // [V, D]
    const float* bias   = (const float*)d_in[4];   // [V]
    const float* Wc     = (const float*)d_in[5];   // [1, D]
    const float* bc     = (const float*)d_in[6];   // [1]
    float* out = (float*)d_out;                    // [N, V]

    // workspace layout (256B-aligned slots)
    const size_t wb_bytes   = (size_t)VOCAB * DIM * 2;          //  32.8 MB
    const size_t hb_bytes   = (size_t)N_ROWS * DIM * 2;         //   2.1 MB
    const size_t cb_bytes   = (size_t)N_ROWS * VOCAB * 2;       // 131.1 MB (bf16 logits)
    const size_t vec_bytes  = (size_t)N_ROWS * 4;               //   8 KB each
    const size_t part_bytes = (size_t)N_ROWS * NT * 8;          //   4.1 MB
    const size_t side_bytes = (size_t)N_ROWS * S_LEN * 4;       //   3.3 MB each

    size_t off = 0;
    auto alloc = [&](size_t bytes) { size_t o = off; off = (off + bytes + 255) & ~(size_t)255; return o; };
    char* ws = (char*)d_ws;
    const size_t o_wb   = alloc(wb_bytes);
    const size_t o_hb   = alloc(hb_bytes);
    const size_t o_cb   = alloc(cb_bytes);
    const size_t o_pc   = alloc(vec_bytes);
    const size_t o_lf   = alloc(vec_bytes);
    const size_t o_sum  = alloc(vec_bytes);
    const size_t o_part = alloc(part_bytes);
    const size_t o_sidx = alloc(side_bytes);
    const size_t o_sval = alloc(side_bytes);
    const size_t need = off;

    if (ws_size >= need) {
        unsigned short* Wb = (unsigned short*)(ws + o_wb);
        unsigned short* Hb = (unsigned short*)(ws + o_hb);
        unsigned short* Cb = (unsigned short*)(ws + o_cb);
        float*  pc       = (float*)(ws + o_pc);
        float*  lfv      = (float*)(ws + o_lf);
        float2* partials = (float2*)(ws + o_part);
        int*    sidx     = (int*)(ws + o_sidx);
        float*  sval     = (float*)(ws + o_sval);

        cast2_bf16_kernel<<<2048, 256, 0, stream>>>(W, Wb, (unsigned)(VOCAB * DIM / 4),
                                                    hidden, Hb, (unsigned)(N_ROWS * DIM / 4));
        pcopy_kernel<<<N_ROWS, 64, 0, stream>>>(hidden, Wc, bc, pc);

        const int nwg = (VOCAB / TBN) * (N_ROWS / TBM);   // 4000
        gemm_mfma_kernel<<<nwg, 256, 0, stream>>>(Hb, Wb, bias, Cb, partials);

        fixup_kernel<<<N_ROWS, 256, 0, stream>>>(partials, Cb, attn, src, pc,
                                                 lfv, sidx, sval);
        scalelog_kernel<<<8192, 256, 0, stream>>>(Cb, out, lfv);
        apply_kernel<<<(N_ROWS * S_LEN + 255) / 256, 256, 0, stream>>>(sidx, sval, out);
    } else {
        float* pc     = (float*)(ws + o_pc);
        float* rowmax = (float*)(ws + o_lf);
        float* rowsum = (float*)(ws + o_sum);

        pcopy_fb_kernel<<<N_ROWS, 64, 0, stream>>>(hidden, Wc, bc, pc);
        dim3 ggrid(VOCAB / BN, N_ROWS / BM);
        gemm_kernel<<<ggrid, 256, 0, stream>>>(hidden, W, bias, out);
        rowstat_kernel<<<N_ROWS, 256, 0, stream>>>(out, rowmax, rowsum);
        scale_kernel<<<4096, 256, 0, stream>>>(out, pc, rowmax, rowsum);
        scatter_kernel<<<(N_ROWS * S_LEN + 255) / 256, 256, 0, stream>>>(out, attn, src, pc);
        log_kernel<<<4096, 256, 0, stream>>>(out);
    }
}